// Round 2
// baseline (497.438 us; speedup 1.0000x reference)
//
#include <hip/hip_runtime.h>
#include <stdint.h>

#define LL 1024
#define NB 8
#define EE 1024
#define HH 16
#define DD 64
#define MM (LL*NB)      // 8192 rows (l*NB+n)
#define K3 (3*EE)       // 3072

typedef __attribute__((ext_vector_type(8))) short bf16x8;   // 8 bf16 in 4 VGPRs
typedef __attribute__((ext_vector_type(4))) float f32x4;
typedef __attribute__((ext_vector_type(2))) float f32x2;
typedef __attribute__((ext_vector_type(4))) unsigned short u16x4;
typedef __attribute__((ext_vector_type(2))) unsigned short u16x2;

__device__ __forceinline__ unsigned short f2bf(float f) {
  uint32_t u = __builtin_bit_cast(uint32_t, f);
  u += 0x7fffu + ((u >> 16) & 1u);           // RNE
  return (unsigned short)(u >> 16);
}
__device__ __forceinline__ float bf2f(unsigned short h) {
  return __builtin_bit_cast(float, ((uint32_t)h) << 16);
}
__device__ __forceinline__ f32x4 mfma16(bf16x8 a, bf16x8 b, f32x4 c) {
  return __builtin_amdgcn_mfma_f32_16x16x32_bf16(a, b, c, 0, 0, 0);
}
__device__ __forceinline__ void gload16(const unsigned short* src, unsigned short* dst) {
  __builtin_amdgcn_global_load_lds(
      (const __attribute__((address_space(1))) uint32_t*)src,
      (__attribute__((address_space(3))) uint32_t*)dst, 16, 0, 0);
}

// ---------------- fp32 -> bf16 convert ----------------
__global__ void cvt_kernel(const float* __restrict__ src, unsigned short* __restrict__ dst, int n4) {
  for (int i = blockIdx.x * blockDim.x + threadIdx.x; i < n4; i += gridDim.x * blockDim.x) {
    f32x4 v = ((const f32x4*)src)[i];
    u16x4 o;
    o[0] = f2bf(v[0]); o[1] = f2bf(v[1]); o[2] = f2bf(v[2]); o[3] = f2bf(v[3]);
    ((u16x4*)dst)[i] = o;
  }
}

// ---------------- GEMM: C[m][c] = sum_k A[m][k]*B[c][k] + bias[c] ----------------
// MODE 0: fp32 out C[m][NN].  MODE 1: bf16 out routed per column region:
//   c in [0,1024)    -> qo[m][c]
//   c in [1024,2048) -> kto[n][h][l][d]   (n=m&7, l=m>>3, h=(c-1024)/64, d=c%64)
//   c in [2048,3072) -> vo[m][c-2048]
template<int MODE>
__global__ __launch_bounds__(256) void gemm_bt(
    const unsigned short* __restrict__ A, const unsigned short* __restrict__ B,
    const float* __restrict__ bias, float* __restrict__ Cf,
    unsigned short* __restrict__ qo, unsigned short* __restrict__ kto,
    unsigned short* __restrict__ vo, int NN, int KDIM)
{
  __shared__ __align__(16) unsigned short a_lds[128 * 32];
  __shared__ __align__(16) unsigned short b_lds[128 * 32];

  const int nwg = gridDim.x;
  const int bid = blockIdx.x;
  const int q8 = nwg >> 3;                       // nwg % 8 == 0 for all our grids
  const int swz = (bid & 7) * q8 + (bid >> 3);   // XCD-aware bijective remap
  const int brow = swz & 63;                     // 64 row tiles
  const int bcol = swz >> 6;

  const int tid = threadIdx.x;
  const int w = tid >> 6, lane = tid & 63;
  const int wr = w >> 1, wc = w & 1;
  const int lrow = lane & 15, g = lane >> 4;

  f32x4 acc[4][4];
#pragma unroll
  for (int i = 0; i < 4; ++i)
#pragma unroll
    for (int j = 0; j < 4; ++j) acc[i][j] = (f32x4){0.f, 0.f, 0.f, 0.f};

  const int r_in = lane >> 2;
  const int u = lane & 3;

  auto stage = [&](int kt) {
    const size_t kcol = (size_t)kt * 32 + u * 8;
    gload16(A + (size_t)(brow * 128 + 16 * w + r_in) * KDIM + kcol,       &a_lds[(16 * w) * 32]);
    gload16(A + (size_t)(brow * 128 + 16 * (w + 4) + r_in) * KDIM + kcol, &a_lds[(16 * (w + 4)) * 32]);
    gload16(B + (size_t)(bcol * 128 + 16 * w + r_in) * KDIM + kcol,       &b_lds[(16 * w) * 32]);
    gload16(B + (size_t)(bcol * 128 + 16 * (w + 4) + r_in) * KDIM + kcol, &b_lds[(16 * (w + 4)) * 32]);
  };

  const int KT = KDIM >> 5;
  stage(0);
  for (int kt = 0; kt < KT; ++kt) {
    __syncthreads();
    bf16x8 af[4], bfr[4];
#pragma unroll
    for (int mt = 0; mt < 4; ++mt)
      af[mt] = *(const bf16x8*)&a_lds[(wr * 64 + mt * 16 + lrow) * 32 + g * 8];
#pragma unroll
    for (int nt = 0; nt < 4; ++nt)
      bfr[nt] = *(const bf16x8*)&b_lds[(wc * 64 + nt * 16 + lrow) * 32 + g * 8];
#pragma unroll
    for (int mt = 0; mt < 4; ++mt)
#pragma unroll
      for (int nt = 0; nt < 4; ++nt)
        acc[mt][nt] = mfma16(af[mt], bfr[nt], acc[mt][nt]);
    __syncthreads();
    if (kt + 1 < KT) stage(kt + 1);
  }

  // epilogue: C layout col = lane&15, row = (lane>>4)*4 + j
#pragma unroll
  for (int nt = 0; nt < 4; ++nt) {
    const int c = bcol * 128 + wc * 64 + nt * 16 + lrow;
    const float bv = bias[c];
#pragma unroll
    for (int mt = 0; mt < 4; ++mt) {
      const int m0 = brow * 128 + wr * 64 + mt * 16 + g * 4;
#pragma unroll
      for (int j = 0; j < 4; ++j) {
        const float val = acc[mt][nt][j] + bv;
        const int m = m0 + j;
        if (MODE == 0) {
          Cf[(size_t)m * NN + c] = val;
        } else {
          const unsigned short b16 = f2bf(val);
          const int region = c >> 10, cl = c & 1023;
          if (region == 0)      qo[(size_t)m * EE + cl] = b16;
          else if (region == 2) vo[(size_t)m * EE + cl] = b16;
          else kto[((size_t)((m & 7) * HH + (cl >> 6)) * LL + (m >> 3)) * DD + (cl & 63)] = b16;
        }
      }
    }
  }
}

// ---------------- V transpose: v[m][1024] -> vt[n][h][d][s] ----------------
__global__ void transpose_v(const unsigned short* __restrict__ v, unsigned short* __restrict__ vt) {
  __shared__ __align__(16) unsigned short tile[64][68];
  const int b = blockIdx.x;                 // 8*16*16 = 2048
  const int lchunk = b & 15, h = (b >> 4) & 15, n = b >> 8;
  const int t = threadIdx.x;
  const int c4 = (t & 15) * 4, r = t >> 4;
#pragma unroll
  for (int p = 0; p < 4; ++p) {
    const int l = lchunk * 64 + p * 16 + r;
    u16x4 x = *(const u16x4*)&v[(size_t)(l * NB + n) * EE + h * DD + c4];
    *(u16x4*)&tile[p * 16 + r][c4] = x;
  }
  __syncthreads();
#pragma unroll
  for (int p = 0; p < 4; ++p) {
    const int d = p * 16 + r;
    u16x4 o;
#pragma unroll
    for (int i = 0; i < 4; ++i) o[i] = tile[c4 + i][d];
    *(u16x4*)&vt[((size_t)(n * HH + h) * DD + d) * LL + lchunk * 64 + c4] = o;
  }
}

// ---------------- fused attention: wave = head, full s per wave ----------------
// grid 512 = n(8, inner for XCD-L2 locality) x l-tile(64 of 16 rows)
// block 1024 = 16 waves; wave w handles head w for the block's 16 q-rows.
__global__ __launch_bounds__(1024, 4) void attn_fused(
    const unsigned short* __restrict__ q,    // [m][1024]
    const unsigned short* __restrict__ kt,   // [n][h][s][d]
    const unsigned short* __restrict__ vt,   // [n][h][d][s]
    unsigned short* __restrict__ ctxo,       // [m][1024] bf16
    float* __restrict__ attn_out)            // [n][1024][1024]
{
  __shared__ __align__(16) unsigned short p_lds[16][16][136];  // [head][l][s-chunk]

  const int bid = blockIdx.x;
  const int n = bid & 7;
  const int lt = (bid >> 3) << 4;
  const int tid = threadIdx.x;
  const int w = tid >> 6;                   // wave index == head
  const int lane = tid & 63;
  const int ll = lane & 15, g = lane >> 4;

  const unsigned short* qrow = q + (size_t)((lt + ll) * NB + n) * EE + w * DD + g * 8;
  const bf16x8 qf0 = *(const bf16x8*)qrow;
  const bf16x8 qf1 = *(const bf16x8*)(qrow + 32);

  const unsigned short* kbase = kt + (size_t)(n * HH + w) * LL * DD + (size_t)ll * DD + g * 8;
  const unsigned short* vbase = vt + (size_t)(n * HH + w) * DD * LL;

  // ---- pass 1: softmax denominators (no max subtraction; |logit| ~ 5) ----
  f32x4 sum4 = (f32x4){0.f, 0.f, 0.f, 0.f};
#pragma unroll 4
  for (int st = 0; st < 64; ++st) {
    const unsigned short* kp = kbase + (size_t)st * (16 * DD);
    bf16x8 kf0 = *(const bf16x8*)kp;
    bf16x8 kf1 = *(const bf16x8*)(kp + 32);
    f32x4 sc = (f32x4){0.f, 0.f, 0.f, 0.f};
    sc = mfma16(kf0, qf0, sc);
    sc = mfma16(kf1, qf1, sc);
#pragma unroll
    for (int j = 0; j < 4; ++j) sum4[j] += __expf(sc[j] * 0.125f);
  }
  float sum = sum4[0] + sum4[1] + sum4[2] + sum4[3];
  sum += __shfl_xor(sum, 16);
  sum += __shfl_xor(sum, 32);
  const float rinv = 1.0f / sum;

  f32x4 ctx[4];
#pragma unroll
  for (int i = 0; i < 4; ++i) ctx[i] = (f32x4){0.f, 0.f, 0.f, 0.f};

  // ---- pass 2: 8 chunks of 128 s ----
  for (int ch = 0; ch < 8; ++ch) {
#pragma unroll 4
    for (int st = 0; st < 8; ++st) {
      const unsigned short* kp = kbase + (size_t)(ch * 8 + st) * (16 * DD);
      bf16x8 kf0 = *(const bf16x8*)kp;
      bf16x8 kf1 = *(const bf16x8*)(kp + 32);
      f32x4 sc = (f32x4){0.f, 0.f, 0.f, 0.f};
      sc = mfma16(kf0, qf0, sc);
      sc = mfma16(kf1, qf1, sc);
      u16x4 pw;
#pragma unroll
      for (int j = 0; j < 4; ++j) pw[j] = f2bf(__expf(sc[j] * 0.125f) * rinv);
      *(u16x4*)&p_lds[w][ll][st * 16 + g * 4] = pw;
    }
    __syncthreads();
    // attention-mean: wave w reduces q-row (lt+w) over all 16 head slabs
    {
      float a0 = 0.f, a1 = 0.f;
#pragma unroll
      for (int hh = 0; hh < 16; ++hh) {
        u16x2 pv = *(const u16x2*)&p_lds[hh][w][lane * 2];
        a0 += bf2f(pv[0]); a1 += bf2f(pv[1]);
      }
      f32x2 o; o[0] = a0 * 0.0625f; o[1] = a1 * 0.0625f;
      *(f32x2*)&attn_out[((size_t)n * LL + lt + w) * LL + ch * 128 + lane * 2] = o;
    }
    // PV: ctx^T += V^T . P^T over this chunk
    bf16x8 pf[4];
#pragma unroll
    for (int ks = 0; ks < 4; ++ks) pf[ks] = *(const bf16x8*)&p_lds[w][ll][ks * 32 + g * 8];
#pragma unroll
    for (int dt = 0; dt < 4; ++dt) {
      const unsigned short* vp = vbase + (size_t)(dt * 16 + ll) * LL + ch * 128 + g * 8;
#pragma unroll
      for (int ks = 0; ks < 4; ++ks) {
        bf16x8 vf = *(const bf16x8*)(vp + ks * 32);
        ctx[dt] = mfma16(vf, pf[ks], ctx[dt]);
      }
    }
    __syncthreads();
  }
  // ---- write ctx: lane (ll,g) reg j holds ctx[d = dt*16+g*4+j][l = ll] ----
#pragma unroll
  for (int dt = 0; dt < 4; ++dt) {
    u16x4 o;
#pragma unroll
    for (int j = 0; j < 4; ++j) o[j] = f2bf(ctx[dt][j]);
    *(u16x4*)&ctxo[(size_t)((lt + ll) * NB + n) * EE + w * DD + dt * 16 + g * 4] = o;
  }
}

extern "C" void kernel_launch(void* const* d_in, const int* in_sizes, int n_in,
                              void* d_out, int out_size, void* d_ws, size_t ws_size,
                              hipStream_t stream) {
  const float* x   = (const float*)d_in[0];
  const float* win = (const float*)d_in[1];
  const float* bin = (const float*)d_in[2];
  const float* ow  = (const float*)d_in[3];
  const float* ob  = (const float*)d_in[4];
  float* out = (float*)d_out;

  const size_t need = ((size_t)MM * EE * 5 + (size_t)K3 * EE + (size_t)EE * EE) * 2;
  if (ws_size < need) return;

  unsigned short* ws  = (unsigned short*)d_ws;
  unsigned short* xb  = ws;                        // [8192][1024]  (reused as ctx)
  unsigned short* wb  = xb + (size_t)MM * EE;      // [3072][1024]
  unsigned short* owb = wb + (size_t)K3 * EE;      // [1024][1024]
  unsigned short* qb  = owb + (size_t)EE * EE;     // [8192][1024]
  unsigned short* ktb = qb + (size_t)MM * EE;      // [8][16][1024][64]
  unsigned short* vb  = ktb + (size_t)MM * EE;     // [8192][1024]
  unsigned short* vtb = vb + (size_t)MM * EE;      // [8][16][64][1024]
  unsigned short* ctx = xb;

  cvt_kernel<<<2048, 256, 0, stream>>>(x, xb, (MM * EE) / 4);
  cvt_kernel<<<1024, 256, 0, stream>>>(win, wb, (K3 * EE) / 4);
  cvt_kernel<<<512, 256, 0, stream>>>(ow, owb, (EE * EE) / 4);
  gemm_bt<1><<<64 * (K3 / 128), 256, 0, stream>>>(xb, wb, bin, nullptr, qb, ktb, vb, K3, EE);
  transpose_v<<<2048, 256, 0, stream>>>(vb, vtb);
  attn_fused<<<512, 1024, 0, stream>>>(qb, ktb, vtb, ctx, out + (size_t)MM * EE);
  gemm_bt<0><<<64 * (EE / 128), 256, 0, stream>>>(ctx, owb, ob, out, nullptr, nullptr, nullptr, EE, EE);
}